// Round 9
// baseline (152.225 us; speedup 1.0000x reference)
//
#include <hip/hip_runtime.h>
#include <cstdint>

#define HB 8
#define CM 128
#define NHEAD 8
#define NPT 8
#define DHD 16
#define HS 64
#define WS 64
#define LTOT 4096
#define NQA 192   // fused off(128) + attn(64)
#define QAP 196   // qaT LDS pitch (floats): 196%32=4; 32*196*4=25088 B
#define LFP 132   // transpose pitch (floats): 132%32=4 spreads banks

typedef float floatx4 __attribute__((ext_vector_type(4)));
typedef short bf16x8 __attribute__((ext_vector_type(8)));

__device__ __forceinline__ unsigned short f2bf_rne(float x) {
  unsigned u = __float_as_uint(x);
  return (unsigned short)((u + 0x7FFFu + ((u >> 16) & 1)) >> 16);
}
__device__ __forceinline__ void split_bf(float x, unsigned short& h, unsigned short& l) {
  unsigned u = __float_as_uint(x);
  h = (unsigned short)(u >> 16);
  float r = x - __uint_as_float(u & 0xFFFF0000u);
  l = (unsigned short)(__float_as_uint(r) >> 16);
}
__device__ __forceinline__ float fast_tanh(float x) {
  float e = __expf(2.0f * x);
  return 1.0f - 2.0f / (e + 1.0f);
}
// unpack uint4 (8 bf16) -> 2x floatx4, fused multiply-accumulate by scalar wc
__device__ __forceinline__ void bf8_fma(floatx4& oa, floatx4& ob, const uint4 r, const float wc) {
  floatx4 va = {__uint_as_float(r.x << 16), __uint_as_float(r.x & 0xFFFF0000u),
                __uint_as_float(r.y << 16), __uint_as_float(r.y & 0xFFFF0000u)};
  floatx4 vb = {__uint_as_float(r.z << 16), __uint_as_float(r.z & 0xFFFF0000u),
                __uint_as_float(r.w << 16), __uint_as_float(r.w & 0xFFFF0000u)};
  oa += va * wc;
  ob += vb * wc;
}

// Weight prep -> bf16 hi/lo fragment layout: element (n,k) at (k>>3)*Nn*8 + n*8 + (k&7).
__global__ __launch_bounds__(256) void prep(const float* __restrict__ Wv,
                                            const float* __restrict__ Wo,
                                            const float* __restrict__ Wa,
                                            const float* __restrict__ Ww,
                                            const float* __restrict__ bo,
                                            const float* __restrict__ ba,
                                            unsigned short* __restrict__ wf_val,
                                            unsigned short* __restrict__ wf_qa,
                                            unsigned short* __restrict__ wf_out,
                                            float* __restrict__ bias_qa) {
  const int gid = blockIdx.x * 256 + threadIdx.x;  // 14336 = 32 k4 * 448 n
  const int k4 = gid / 448;
  const int ng = gid - k4 * 448;

  const float* src;
  unsigned short* dst;
  int Nsrc, Nn, nd, n;
  if (ng < 128) {        src = Wv; dst = wf_val; Nsrc = 128; Nn = 128; n = ng;        nd = n; }
  else if (ng < 256) {   src = Wo; dst = wf_qa;  Nsrc = 128; Nn = 192; n = ng - 128;  nd = n; }
  else if (ng < 320) {   src = Wa; dst = wf_qa;  Nsrc = 64;  Nn = 192; n = ng - 256;  nd = n + 128; }
  else {                 src = Ww; dst = wf_out; Nsrc = 128; Nn = 128; n = ng - 320;  nd = n; }

  ushort4 hi, lo;
  split_bf(src[(k4 * 4 + 0) * Nsrc + n], hi.x, lo.x);
  split_bf(src[(k4 * 4 + 1) * Nsrc + n], hi.y, lo.y);
  split_bf(src[(k4 * 4 + 2) * Nsrc + n], hi.z, lo.z);
  split_bf(src[(k4 * 4 + 3) * Nsrc + n], hi.w, lo.w);
  const int off = (k4 >> 1) * Nn * 8 + nd * 8 + (k4 & 1) * 4;
  *(ushort4*)(dst + off) = hi;
  *(ushort4*)(dst + Nn * 128 + off) = lo;

  if (gid < 128) bias_qa[gid] = bo[gid];
  else if (gid < 192) bias_qa[gid] = ba[gid - 128];
}

// K1 (R9 "proj"): 2048 blocks, two roles in ONE dispatch so the qa pipeline hides
// under the value projection (independent inputs: nbr vs ext).
//  blocks [0,1024): value projection, R8 body verbatim (32x128 tile).
//  blocks [1024,2048): stage ext -> qa GEMM -> register params -> wpack
//    (px,py,aw f32 per (b,l,h,p); layout [b][l][h][p*3] -> thread writes 96 B
//     contiguous, wave writes 6 KB contiguous; 25 MB, L2-resident for samp2).
// Rationale: samp was issue+chain bound (~80 VMEM/thread, 7 barriers); moving the
// front half here shortens samp2's chain to 2 phases and overlaps qa with gemm_val.
__global__ __launch_bounds__(256, 4) void proj(const float* __restrict__ nbr,
                                               const float* __restrict__ ext,
                                               const unsigned short* __restrict__ wf_val,
                                               const float* __restrict__ b_val,
                                               const unsigned short* __restrict__ wf_qa,
                                               const float* __restrict__ bias_qa,
                                               unsigned short* __restrict__ value,
                                               float* __restrict__ wpack) {
  __shared__ __align__(16) char smem[25088];
  const int t = threadIdx.x;
  const int w = t >> 6, lane = t & 63;
  const int nl = lane & 15, q = lane >> 4;

  if (blockIdx.x < 1024) {
    // ================= value projection role (R8 gemm_val) =================
    const int bx = blockIdx.x;
    const int b = bx >> 7;
    const int ml0 = (bx & 127) * 32;
    unsigned short* AB = (unsigned short*)smem;  // hi [32][128]; lo at +4096 us
    {
      const float* src = nbr + (size_t)b * CM * LTOT + ml0;
      const int x = t & 31, kq = t >> 5;  // kq 0..7
#pragma unroll
      for (int i = 0; i < 4; i++) {
        const int kb = i * 32 + kq * 4;
        ushort4 hi, lo;
        split_bf(src[(size_t)(kb + 0) * LTOT + x], hi.x, lo.x);
        split_bf(src[(size_t)(kb + 1) * LTOT + x], hi.y, lo.y);
        split_bf(src[(size_t)(kb + 2) * LTOT + x], hi.z, lo.z);
        split_bf(src[(size_t)(kb + 3) * LTOT + x], hi.w, lo.w);
        const int off = x * 128 + (((kb >> 3) ^ (x & 15)) << 3) + (kb & 7);
        *(ushort4*)(AB + off) = hi;
        *(ushort4*)(AB + 4096 + off) = lo;
      }
    }
    __syncthreads();

    const int wm = (w & 1) * 16, wn = (w >> 1) * 64;
    floatx4 acc[4];
#pragma unroll
    for (int j = 0; j < 4; j++) acc[j] = {0.0f, 0.0f, 0.0f, 0.0f};

#pragma unroll
    for (int K0 = 0; K0 < 4; K0++) {
      const int m = wm + nl;
      const int off = m * 128 + (((K0 * 4 + q) ^ (m & 15)) << 3);
      const bf16x8 ah = *(bf16x8*)(AB + off);
      const bf16x8 al = *(bf16x8*)(AB + 4096 + off);
#pragma unroll
      for (int j = 0; j < 4; j++) {
        const size_t o = (size_t)(K0 * 4 + q) * CM * 8 + (wn + j * 16 + nl) * 8;
        const bf16x8 wh = *(const bf16x8*)(wf_val + o);
        const bf16x8 wl = *(const bf16x8*)(wf_val + (size_t)CM * 128 + o);
        acc[j] = __builtin_amdgcn_mfma_f32_16x16x32_bf16(al, wh, acc[j], 0, 0, 0);
        acc[j] = __builtin_amdgcn_mfma_f32_16x16x32_bf16(ah, wl, acc[j], 0, 0, 0);
        acc[j] = __builtin_amdgcn_mfma_f32_16x16x32_bf16(ah, wh, acc[j], 0, 0, 0);
      }
    }

    __syncthreads();  // AB dead
    float* LF = (float*)smem;
#pragma unroll
    for (int j = 0; j < 4; j++) {
      const int gc = wn + j * 16 + nl;
      const float bv = b_val[gc];
#pragma unroll
      for (int r = 0; r < 4; r++)
        LF[(wm + q * 4 + r) * LFP + gc] = acc[j][r] + bv;
    }
    __syncthreads();
#pragma unroll
    for (int i = 0; i < 2; i++) {
      const int c = t + i * 256;
      const int h = c >> 6, rem = c & 63, l = rem >> 1, half = rem & 1;
      const float* sp = LF + l * LFP + h * 16 + half * 8;
      uint4 st;
      st.x = ((unsigned)f2bf_rne(sp[1]) << 16) | f2bf_rne(sp[0]);
      st.y = ((unsigned)f2bf_rne(sp[3]) << 16) | f2bf_rne(sp[2]);
      st.z = ((unsigned)f2bf_rne(sp[5]) << 16) | f2bf_rne(sp[4]);
      st.w = ((unsigned)f2bf_rne(sp[7]) << 16) | f2bf_rne(sp[6]);
      *(uint4*)(value + ((size_t)(b * NHEAD + h) * LTOT + ml0 + l) * DHD + half * 8) = st;
    }
  } else {
    // ================= qa role (R6 front half + register params) =================
    const int i0 = blockIdx.x - 1024;
    const int b = i0 & 7;
    const int ml0 = (i0 >> 3) * 32;
    unsigned short* AB = (unsigned short*)smem;  // [32][128] hi; lo at +4096 us
    float* qaT = (float*)smem;                   // [32][QAP] = 25088 B (after AB dead)
    {
      const float* src = ext + (size_t)b * CM * LTOT + ml0;
      const int x = t & 31, kq = t >> 5;  // kq 0..7
#pragma unroll
      for (int i = 0; i < 4; i++) {
        const int kb = i * 32 + kq * 4;
        ushort4 hi, lo;
        split_bf(src[(size_t)(kb + 0) * LTOT + x], hi.x, lo.x);
        split_bf(src[(size_t)(kb + 1) * LTOT + x], hi.y, lo.y);
        split_bf(src[(size_t)(kb + 2) * LTOT + x], hi.z, lo.z);
        split_bf(src[(size_t)(kb + 3) * LTOT + x], hi.w, lo.w);
        const int off = x * 128 + (((kb >> 3) ^ (x & 15)) << 3) + (kb & 7);
        *(ushort4*)(AB + off) = hi;
        *(ushort4*)(AB + 4096 + off) = lo;
      }
    }
    __syncthreads();

    {  // qa GEMM: 32m x 192n, 4 waves, wave = 16m x 96n
      const int wm = (w & 1) * 16;
      const int wn = (w >> 1) * 96;
      floatx4 acc[6];
#pragma unroll
      for (int j = 0; j < 6; j++) acc[j] = {0.0f, 0.0f, 0.0f, 0.0f};
#pragma unroll
      for (int K0 = 0; K0 < 4; K0++) {
        const int m = wm + nl;
        const int off = m * 128 + (((K0 * 4 + q) ^ (m & 15)) << 3);
        const bf16x8 ah = *(bf16x8*)(AB + off);
        const bf16x8 al = *(bf16x8*)(AB + 4096 + off);
#pragma unroll
        for (int j = 0; j < 6; j++) {
          const size_t o = (size_t)(K0 * 4 + q) * NQA * 8 + (wn + j * 16 + nl) * 8;
          const bf16x8 wh = *(const bf16x8*)(wf_qa + o);
          const bf16x8 wl = *(const bf16x8*)(wf_qa + (size_t)NQA * 128 + o);
          acc[j] = __builtin_amdgcn_mfma_f32_16x16x32_bf16(al, wh, acc[j], 0, 0, 0);
          acc[j] = __builtin_amdgcn_mfma_f32_16x16x32_bf16(ah, wl, acc[j], 0, 0, 0);
          acc[j] = __builtin_amdgcn_mfma_f32_16x16x32_bf16(ah, wh, acc[j], 0, 0, 0);
        }
      }
      __syncthreads();  // all AB reads done -> qaT may overwrite
#pragma unroll
      for (int j = 0; j < 6; j++) {
        const int n = wn + j * 16 + nl;
        const float bv = bias_qa[n];
#pragma unroll
        for (int r = 0; r < 4; r++)
          qaT[(wm + q * 4 + r) * QAP + n] = acc[j][r] + bv;
      }
    }
    __syncthreads();

    {  // params: thread (ll = t>>3, h = t&7) -> registers -> wpack (96 B/thread)
      const int ll = t >> 3, h = t & 7;
      const float* qrow = qaT + ll * QAP;
      float4 of[4];
#pragma unroll
      for (int j = 0; j < 4; j++) of[j] = *(const float4*)(qrow + h * 16 + j * 4);
      const float4 lga = *(const float4*)(qrow + 128 + h * 8);
      const float4 lgb = *(const float4*)(qrow + 128 + h * 8 + 4);
      const float lg[8] = {lga.x, lga.y, lga.z, lga.w, lgb.x, lgb.y, lgb.z, lgb.w};
      float m = lg[0];
#pragma unroll
      for (int p = 1; p < 8; p++) m = fmaxf(m, lg[p]);
      float e[8], s = 0.0f;
#pragma unroll
      for (int p = 0; p < 8; p++) { e[p] = __expf(lg[p] - m); s += e[p]; }
      const float inv = 1.0f / s;
      const int l = ml0 + ll;
      const float xf = (float)(l & (WS - 1));
      const float yf = (float)(l >> 6);
      float wpl[24];
#pragma unroll
      for (int p = 0; p < 8; p++) {
        const float ox = (p & 1) ? of[p >> 1].z : of[p >> 1].x;
        const float oy = (p & 1) ? of[p >> 1].w : of[p >> 1].y;
        wpl[p * 3 + 0] = xf + 10.0f * fast_tanh(ox);
        wpl[p * 3 + 1] = yf + 10.0f * fast_tanh(oy);
        wpl[p * 3 + 2] = e[p] * inv;
      }
      float* wp = wpack + ((size_t)(b * LTOT + ml0 + ll) * 8 + h) * 24;
#pragma unroll
      for (int j = 0; j < 6; j++)
        *(float4*)(wp + j * 4) = *(float4*)(wpl + j * 4);
    }
  }
}

// K2 (R9 "samp2"): gather + out GEMM only. 1024 blocks x 256 thr. Chain = 2 phases:
// [wpack read + h-sequenced gather -> FR] -> barrier -> [out GEMM]. ~54 VMEM/thread
// (was 80), 1 barrier (was 7). Gather identical to verified R6 (wave w, heads w,w+4;
// lane = (llq, half); L1-window resident). LDS = FR 8192 B only.
__global__ __launch_bounds__(256, 4) void samp2(const unsigned short* __restrict__ value,
                                                const float* __restrict__ wpack,
                                                const unsigned short* __restrict__ wf_out,
                                                const float* __restrict__ b_out,
                                                float* __restrict__ out) {
  __shared__ __align__(16) char smem[8192];
  unsigned short* FR = (unsigned short*)smem;  // [32][128] bf16

  const int t = threadIdx.x;
  const int b = blockIdx.x & 7;                // XCD affinity
  const int ml0 = (blockIdx.x >> 3) * 32;
  const int w = t >> 6, lane = t & 63;
  const int nl = lane & 15, q = lane >> 4;

  {
    const int llq = lane >> 1, half = lane & 1;
    const int llm = llq & 15;
#pragma unroll
    for (int hi2 = 0; hi2 < 2; hi2++) {
      const int hh = w + hi2 * 4;  // wave-uniform head
      const float* wp = wpack + ((size_t)(b * LTOT + ml0 + llq) * 8 + hh) * 24;
      float wpl[24];
#pragma unroll
      for (int j = 0; j < 6; j++)
        *(float4*)(wpl + j * 4) = *(const float4*)(wp + j * 4);
      const unsigned short* vb = value + (size_t)(b * NHEAD + hh) * LTOT * DHD + half * 8;
      floatx4 oa = {0.f, 0.f, 0.f, 0.f}, ob = oa;
#pragma unroll
      for (int p = 0; p < 8; p++) {
        const float pxx = wpl[p * 3 + 0];
        const float pyy = wpl[p * 3 + 1];
        const float a = wpl[p * 3 + 2];
        const float x0f = floorf(pxx), y0f = floorf(pyy);
        const float fx = pxx - x0f, fy = pyy - y0f;
        const int ix = (int)x0f, iy = (int)y0f;
        float wc[4];
        unsigned adr[4];
#pragma unroll
        for (int c = 0; c < 4; c++) {
          const int cdx = c & 1, cdy = c >> 1;
          const int jx = ix + cdx, jy = iy + cdy;
          const float wx = cdx ? fx : 1.0f - fx;
          const float wy = cdy ? fy : 1.0f - fy;
          const bool valid = ((unsigned)jx < WS) & ((unsigned)jy < HS);
          wc[c] = valid ? a * wx * wy : 0.0f;
          const int cx = min(max(jx, 0), WS - 1);
          const int cy = min(max(jy, 0), HS - 1);
          adr[c] = (unsigned)((cy << 6) + cx) * DHD;
        }
        uint4 r[4];
#pragma unroll
        for (int c = 0; c < 4; c++) r[c] = *(const uint4*)(vb + adr[c]);
#pragma unroll
        for (int c = 0; c < 4; c++) bf8_fma(oa, ob, r[c], wc[c]);
      }
      // FR: group g = hh*2+half holds channels g*8..g*8+7, swizzled by llm
      const int off = llq * 128 + (((hh * 2 + half) ^ llm) << 3);
      uint4 st;
      st.x = ((unsigned)f2bf_rne(oa[1]) << 16) | f2bf_rne(oa[0]);
      st.y = ((unsigned)f2bf_rne(oa[3]) << 16) | f2bf_rne(oa[2]);
      st.z = ((unsigned)f2bf_rne(ob[1]) << 16) | f2bf_rne(ob[0]);
      st.w = ((unsigned)f2bf_rne(ob[3]) << 16) | f2bf_rne(ob[2]);
      *(uint4*)(FR + off) = st;
    }
  }
  __syncthreads();

  // ---- out GEMM: 32m x 128n, 4 waves, wave = 16m x 64n; direct float4 stores ----
  {
    const int wm = (w & 1) * 16;
    const int wn = (w >> 1) * 64;
    floatx4 acc[4];
#pragma unroll
    for (int j = 0; j < 4; j++) acc[j] = {0.0f, 0.0f, 0.0f, 0.0f};
#pragma unroll
    for (int K0 = 0; K0 < 4; K0++) {
      const int m = wm + nl;
      const int off = m * 128 + (((K0 * 4 + q) ^ (m & 15)) << 3);
      const bf16x8 ah = *(bf16x8*)(FR + off);
#pragma unroll
      for (int j = 0; j < 4; j++) {
        const int n = wn + j * 16 + nl;
        const size_t o = (size_t)(K0 * 4 + q) * CM * 8 + n * 8;
        const bf16x8 wh = *(const bf16x8*)(wf_out + o);
        const bf16x8 wl = *(const bf16x8*)(wf_out + (size_t)CM * 128 + o);
        acc[j] = __builtin_amdgcn_mfma_f32_16x16x32_bf16(ah, wl, acc[j], 0, 0, 0);
        acc[j] = __builtin_amdgcn_mfma_f32_16x16x32_bf16(ah, wh, acc[j], 0, 0, 0);
      }
    }
    // C/D: col=nl -> n, rows q*4+r -> m (contiguous in bchw) => float4 store
#pragma unroll
    for (int j = 0; j < 4; j++) {
      const int gc = wn + j * 16 + nl;
      const float bv = b_out[gc];
      float4 st = {acc[j][0] + bv, acc[j][1] + bv, acc[j][2] + bv, acc[j][3] + bv};
      *(float4*)(out + ((size_t)b * CM + gc) * LTOT + ml0 + wm + q * 4) = st;
    }
  }
}

extern "C" void kernel_launch(void* const* d_in, const int* in_sizes, int n_in,
                              void* d_out, int out_size, void* d_ws, size_t ws_size,
                              hipStream_t stream) {
  const float* nbr    = (const float*)d_in[0];
  const float* ext    = (const float*)d_in[1];
  const float* W_val  = (const float*)d_in[2];
  const float* b_val  = (const float*)d_in[3];
  const float* W_off  = (const float*)d_in[4];
  const float* b_off  = (const float*)d_in[5];
  const float* W_attn = (const float*)d_in[6];
  const float* b_attn = (const float*)d_in[7];
  const float* W_out  = (const float*)d_in[8];
  const float* b_out  = (const float*)d_in[9];
  float* out = (float*)d_out;

  unsigned short* value = (unsigned short*)d_ws;             // 8.39 MB bf16 [b][h][l][16]
  unsigned short* wf_val = value + (size_t)HB * NHEAD * LTOT * DHD;  // 64 KB
  unsigned short* wf_qa  = wf_val + 128 * 128 * 2;           // 96 KB
  unsigned short* wf_out = wf_qa + 192 * 128 * 2;            // 64 KB
  float* bias_qa = (float*)(wf_out + 128 * 128 * 2);         // 768 B
  float* wpack   = bias_qa + 192;                            // 25.2 MB [b][l][h][p*3]

  prep<<<56, 256, 0, stream>>>(W_val, W_off, W_attn, W_out, b_off, b_attn,
                               wf_val, wf_qa, wf_out, bias_qa);
  proj<<<2048, 256, 0, stream>>>(nbr, ext, wf_val, b_val, wf_qa, bias_qa, value, wpack);
  samp2<<<1024, 256, 0, stream>>>(value, wpack, wf_out, b_out, out);
}

// Round 10
// 132.314 us; speedup vs baseline: 1.1505x; 1.1505x over previous
//
#include <hip/hip_runtime.h>
#include <cstdint>

#define HB 8
#define CM 128
#define NHEAD 8
#define NPT 8
#define DHD 16
#define HS 64
#define WS 64
#define LTOT 4096
#define NQA 192   // fused off(128) + attn(64)
#define QAP 196   // qaT LDS pitch (floats): 196%32=4; 32*196*4=25088 B
#define LFP 132   // gemm_val transpose pitch (floats): 132%32=4 spreads banks
#define WPP 33    // WXY/WA pitch (entries) per (h,p) row: 33 breaks pow2 banks

typedef float floatx4 __attribute__((ext_vector_type(4)));
typedef short bf16x8 __attribute__((ext_vector_type(8)));

__device__ __forceinline__ unsigned short f2bf_rne(float x) {
  unsigned u = __float_as_uint(x);
  return (unsigned short)((u + 0x7FFFu + ((u >> 16) & 1)) >> 16);
}
__device__ __forceinline__ void split_bf(float x, unsigned short& h, unsigned short& l) {
  unsigned u = __float_as_uint(x);
  h = (unsigned short)(u >> 16);
  float r = x - __uint_as_float(u & 0xFFFF0000u);
  l = (unsigned short)(__float_as_uint(r) >> 16);
}
__device__ __forceinline__ float fast_tanh(float x) {
  float e = __expf(2.0f * x);
  return 1.0f - 2.0f / (e + 1.0f);
}
// unpack uint4 (8 bf16) -> 2x floatx4, fused multiply-accumulate by scalar wc
__device__ __forceinline__ void bf8_fma(floatx4& oa, floatx4& ob, const uint4 r, const float wc) {
  floatx4 va = {__uint_as_float(r.x << 16), __uint_as_float(r.x & 0xFFFF0000u),
                __uint_as_float(r.y << 16), __uint_as_float(r.y & 0xFFFF0000u)};
  floatx4 vb = {__uint_as_float(r.z << 16), __uint_as_float(r.z & 0xFFFF0000u),
                __uint_as_float(r.w << 16), __uint_as_float(r.w & 0xFFFF0000u)};
  oa += va * wc;
  ob += vb * wc;
}

// Weight prep -> bf16 hi/lo fragment layout: element (n,k) at (k>>3)*Nn*8 + n*8 + (k&7).
__global__ __launch_bounds__(256) void prep(const float* __restrict__ Wv,
                                            const float* __restrict__ Wo,
                                            const float* __restrict__ Wa,
                                            const float* __restrict__ Ww,
                                            const float* __restrict__ bo,
                                            const float* __restrict__ ba,
                                            unsigned short* __restrict__ wf_val,
                                            unsigned short* __restrict__ wf_qa,
                                            unsigned short* __restrict__ wf_out,
                                            float* __restrict__ bias_qa) {
  const int gid = blockIdx.x * 256 + threadIdx.x;  // 14336 = 32 k4 * 448 n
  const int k4 = gid / 448;
  const int ng = gid - k4 * 448;

  const float* src;
  unsigned short* dst;
  int Nsrc, Nn, nd, n;
  if (ng < 128) {        src = Wv; dst = wf_val; Nsrc = 128; Nn = 128; n = ng;        nd = n; }
  else if (ng < 256) {   src = Wo; dst = wf_qa;  Nsrc = 128; Nn = 192; n = ng - 128;  nd = n; }
  else if (ng < 320) {   src = Wa; dst = wf_qa;  Nsrc = 64;  Nn = 192; n = ng - 256;  nd = n + 128; }
  else {                 src = Ww; dst = wf_out; Nsrc = 128; Nn = 128; n = ng - 320;  nd = n; }

  ushort4 hi, lo;
  split_bf(src[(k4 * 4 + 0) * Nsrc + n], hi.x, lo.x);
  split_bf(src[(k4 * 4 + 1) * Nsrc + n], hi.y, lo.y);
  split_bf(src[(k4 * 4 + 2) * Nsrc + n], hi.z, lo.z);
  split_bf(src[(k4 * 4 + 3) * Nsrc + n], hi.w, lo.w);
  const int off = (k4 >> 1) * Nn * 8 + nd * 8 + (k4 & 1) * 4;
  *(ushort4*)(dst + off) = hi;
  *(ushort4*)(dst + Nn * 128 + off) = lo;

  if (gid < 128) bias_qa[gid] = bo[gid];
  else if (gid < 192) bias_qa[gid] = ba[gid - 128];
}

// K1 (R8, best-verified): value projection re-tiled for TLP. 32x128 tile, 1024
// blocks (4/CU, 16 waves/CU), wave = 16m x 64n acc[4], 48 MFMA/wave, LDS 16896 B.
// 3-term bf16 split, swizzled staging, coalesced uint4 epilogue.
// R9 lesson: fusing the qa pipeline into this dispatch (mixed roles) regressed —
// +50 MB wpack traffic, LDS back to 25088, no real overlap. Keep kernels separate.
__global__ __launch_bounds__(256, 4) void gemm_val(const float* __restrict__ nbr,
                                                   const unsigned short* __restrict__ WF,
                                                   const float* __restrict__ bias,
                                                   unsigned short* __restrict__ value) {
  __shared__ __align__(16) char smem[16896];   // staging 16384; transpose 32*132*4=16896
  unsigned short* AB = (unsigned short*)smem;  // hi [32][128]; lo at +4096 us
  const int t = threadIdx.x;
  const int ml0 = blockIdx.x * 32;
  const int b = blockIdx.y;

  {
    const float* src = nbr + (size_t)b * CM * LTOT + ml0;
    const int x = t & 31, kq = t >> 5;  // kq 0..7
#pragma unroll
    for (int i = 0; i < 4; i++) {
      const int kb = i * 32 + kq * 4;
      ushort4 hi, lo;
      split_bf(src[(size_t)(kb + 0) * LTOT + x], hi.x, lo.x);
      split_bf(src[(size_t)(kb + 1) * LTOT + x], hi.y, lo.y);
      split_bf(src[(size_t)(kb + 2) * LTOT + x], hi.z, lo.z);
      split_bf(src[(size_t)(kb + 3) * LTOT + x], hi.w, lo.w);
      const int off = x * 128 + (((kb >> 3) ^ (x & 15)) << 3) + (kb & 7);
      *(ushort4*)(AB + off) = hi;
      *(ushort4*)(AB + 4096 + off) = lo;
    }
  }
  __syncthreads();

  const int w = t >> 6, lane = t & 63;
  const int wm = (w & 1) * 16, wn = (w >> 1) * 64;
  const int nl = lane & 15, q = lane >> 4;

  floatx4 acc[4];
#pragma unroll
  for (int j = 0; j < 4; j++) acc[j] = {0.0f, 0.0f, 0.0f, 0.0f};

#pragma unroll
  for (int K0 = 0; K0 < 4; K0++) {
    const int m = wm + nl;
    const int off = m * 128 + (((K0 * 4 + q) ^ (m & 15)) << 3);
    const bf16x8 ah = *(bf16x8*)(AB + off);
    const bf16x8 al = *(bf16x8*)(AB + 4096 + off);
#pragma unroll
    for (int j = 0; j < 4; j++) {
      const size_t o = (size_t)(K0 * 4 + q) * CM * 8 + (wn + j * 16 + nl) * 8;
      const bf16x8 wh = *(const bf16x8*)(WF + o);
      const bf16x8 wl = *(const bf16x8*)(WF + (size_t)CM * 128 + o);
      acc[j] = __builtin_amdgcn_mfma_f32_16x16x32_bf16(al, wh, acc[j], 0, 0, 0);
      acc[j] = __builtin_amdgcn_mfma_f32_16x16x32_bf16(ah, wl, acc[j], 0, 0, 0);
      acc[j] = __builtin_amdgcn_mfma_f32_16x16x32_bf16(ah, wh, acc[j], 0, 0, 0);
    }
  }

  // ---- epilogue: acc -> LDS [32 l][132] fp32 -> packed bf16 uint4 coalesced stores ----
  __syncthreads();  // AB dead
  float* LF = (float*)smem;
#pragma unroll
  for (int j = 0; j < 4; j++) {
    const int gc = wn + j * 16 + nl;
    const float bv = bias[gc];
#pragma unroll
    for (int r = 0; r < 4; r++)
      LF[(wm + q * 4 + r) * LFP + gc] = acc[j][r] + bv;
  }
  __syncthreads();
  // 512 uint4 chunks: c = h(3b) | l(5b) | half(1b); wave writes contiguous 1 KB per h
#pragma unroll
  for (int i = 0; i < 2; i++) {
    const int c = t + i * 256;
    const int h = c >> 6, rem = c & 63, l = rem >> 1, half = rem & 1;
    const float* sp = LF + l * LFP + h * 16 + half * 8;
    uint4 st;
    st.x = ((unsigned)f2bf_rne(sp[1]) << 16) | f2bf_rne(sp[0]);
    st.y = ((unsigned)f2bf_rne(sp[3]) << 16) | f2bf_rne(sp[2]);
    st.z = ((unsigned)f2bf_rne(sp[5]) << 16) | f2bf_rne(sp[4]);
    st.w = ((unsigned)f2bf_rne(sp[7]) << 16) | f2bf_rne(sp[6]);
    *(uint4*)(value + ((size_t)(b * NHEAD + h) * LTOT + ml0 + l) * DHD + half * 8) = st;
  }
}

// K2 (R7/R8, best-verified): 512 thr, h-sequenced gather, WXY/WA handoff.
// samp proven invariant (~43-45us) to occupancy 17->63%, instr count 2x, line
// layout (R5), phase splitting (R9); remaining time = compulsory gather traffic
// + issue floor. Parked at its best-known form.
__global__ __launch_bounds__(512, 2) void samp(const float* __restrict__ ext,
                                               const unsigned short* __restrict__ value,
                                               const unsigned short* __restrict__ wf_qa,
                                               const unsigned short* __restrict__ wf_out,
                                               const float* __restrict__ bias_qa,
                                               const float* __restrict__ b_out,
                                               float* __restrict__ out) {
  __shared__ __align__(16) char smem[33792];
  unsigned short* AB = (unsigned short*)smem;   // [0,16384): staging hi/lo
  float* qaT = (float*)smem;                    // [0,25088)
  float2* WXY = (float2*)smem;                  // [8h*8p][WPP] float2 = 16896 B at 0
  float* WA = (float*)(smem + 16896);           // [8h*8p][WPP] float  =  8448 B
  unsigned short* FR = (unsigned short*)(smem + 25344);  // [32][128] bf16 = 8192 B

  const int t = threadIdx.x;
  const int b = blockIdx.x & 7;                // XCD affinity
  const int ml0 = (blockIdx.x >> 3) * 32;
  const int w = t >> 6, lane = t & 63;
  const int nl = lane & 15, q = lane >> 4;

  // ---- stage ext 32-l tile (fp32 -> bf16 hi/lo, swizzled); 512 thr -> 2 iters ----
  {
    const float* src = ext + (size_t)b * CM * LTOT + ml0;
    const int x = t & 31, kq = t >> 5;  // kq 0..15
#pragma unroll
    for (int i = 0; i < 2; i++) {
      const int kb = i * 64 + kq * 4;
      ushort4 hi, lo;
      split_bf(src[(size_t)(kb + 0) * LTOT + x], hi.x, lo.x);
      split_bf(src[(size_t)(kb + 1) * LTOT + x], hi.y, lo.y);
      split_bf(src[(size_t)(kb + 2) * LTOT + x], hi.z, lo.z);
      split_bf(src[(size_t)(kb + 3) * LTOT + x], hi.w, lo.w);
      const int off = x * 128 + (((kb >> 3) ^ (x & 15)) << 3) + (kb & 7);
      *(ushort4*)(AB + off) = hi;
      *(ushort4*)(AB + 4096 + off) = lo;
    }
  }
  __syncthreads();

  // ---- qa GEMM: 32m x 192n, 8 waves, wave = 16m x 48n; result -> qaT (LDS) ----
  {
    const int wm = (w & 1) * 16;
    const int wn = (w >> 1) * 48;
    floatx4 acc[3];
#pragma unroll
    for (int j = 0; j < 3; j++) acc[j] = {0.0f, 0.0f, 0.0f, 0.0f};
#pragma unroll
    for (int K0 = 0; K0 < 4; K0++) {
      const int m = wm + nl;
      const int off = m * 128 + (((K0 * 4 + q) ^ (m & 15)) << 3);
      const bf16x8 ah = *(bf16x8*)(AB + off);
      const bf16x8 al = *(bf16x8*)(AB + 4096 + off);
#pragma unroll
      for (int j = 0; j < 3; j++) {
        const size_t o = (size_t)(K0 * 4 + q) * NQA * 8 + (wn + j * 16 + nl) * 8;
        const bf16x8 wh = *(const bf16x8*)(wf_qa + o);
        const bf16x8 wl = *(const bf16x8*)(wf_qa + (size_t)NQA * 128 + o);
        acc[j] = __builtin_amdgcn_mfma_f32_16x16x32_bf16(al, wh, acc[j], 0, 0, 0);
        acc[j] = __builtin_amdgcn_mfma_f32_16x16x32_bf16(ah, wl, acc[j], 0, 0, 0);
        acc[j] = __builtin_amdgcn_mfma_f32_16x16x32_bf16(ah, wh, acc[j], 0, 0, 0);
      }
    }
    __syncthreads();  // all AB reads done -> qaT may overwrite
#pragma unroll
    for (int j = 0; j < 3; j++) {
      const int n = wn + j * 16 + nl;
      const float bv = bias_qa[n];
#pragma unroll
      for (int r = 0; r < 4; r++)
        qaT[(wm + q * 4 + r) * QAP + n] = acc[j][r] + bv;
    }
  }
  __syncthreads();

  // ---- sampling params: threads t<256, (ll = t>>3, h = t&7) -> WXY/WA LDS ----
  {
    float4 of[4];
    float4 lga = {0, 0, 0, 0}, lgb = {0, 0, 0, 0};
    const int ll = t >> 3, h = t & 7;
    if (t < 256) {
      const float* qrow = qaT + ll * QAP;
#pragma unroll
      for (int j = 0; j < 4; j++) of[j] = *(const float4*)(qrow + h * 16 + j * 4);
      lga = *(const float4*)(qrow + 128 + h * 8);
      lgb = *(const float4*)(qrow + 128 + h * 8 + 4);
    }
    __syncthreads();  // qaT fully read -> WXY/WA may overwrite
    if (t < 256) {
      const float lg[8] = {lga.x, lga.y, lga.z, lga.w, lgb.x, lgb.y, lgb.z, lgb.w};
      float m = lg[0];
#pragma unroll
      for (int p = 1; p < 8; p++) m = fmaxf(m, lg[p]);
      float e[8], s = 0.0f;
#pragma unroll
      for (int p = 0; p < 8; p++) { e[p] = __expf(lg[p] - m); s += e[p]; }
      const float inv = 1.0f / s;
      const int l = ml0 + ll;
      const float xf = (float)(l & (WS - 1));
      const float yf = (float)(l >> 6);
#pragma unroll
      for (int p = 0; p < 8; p++) {
        const float ox = (p & 1) ? of[p >> 1].z : of[p >> 1].x;
        const float oy = (p & 1) ? of[p >> 1].w : of[p >> 1].y;
        WXY[(h * 8 + p) * WPP + ll] = {xf + 10.0f * fast_tanh(ox), yf + 10.0f * fast_tanh(oy)};
        WA[(h * 8 + p) * WPP + ll] = e[p] * inv;
      }
    }
  }
  __syncthreads();

  // ---- gather: wave w owns head w; lane = (llq = lane>>1, half = lane&1) ----
  {
    const int llq = lane >> 1, half = lane & 1;
    const int llm = llq & 15;
    const unsigned short* vb = value + (size_t)(b * NHEAD + w) * LTOT * DHD + half * 8;
    floatx4 oa = {0.f, 0.f, 0.f, 0.f}, ob = oa;
#pragma unroll
    for (int p = 0; p < 8; p++) {
      const float2 pxy = WXY[(w * 8 + p) * WPP + llq];
      const float a = WA[(w * 8 + p) * WPP + llq];
      const float x0f = floorf(pxy.x), y0f = floorf(pxy.y);
      const float fx = pxy.x - x0f, fy = pxy.y - y0f;
      const int ix = (int)x0f, iy = (int)y0f;
      float wc[4];
      unsigned adr[4];
#pragma unroll
      for (int c = 0; c < 4; c++) {
        const int cdx = c & 1, cdy = c >> 1;
        const int jx = ix + cdx, jy = iy + cdy;
        const float wx = cdx ? fx : 1.0f - fx;
        const float wy = cdy ? fy : 1.0f - fy;
        const bool valid = ((unsigned)jx < WS) & ((unsigned)jy < HS);
        wc[c] = valid ? a * wx * wy : 0.0f;
        const int cx = min(max(jx, 0), WS - 1);
        const int cy = min(max(jy, 0), HS - 1);
        adr[c] = (unsigned)((cy << 6) + cx) * DHD;
      }
      uint4 r[4];
#pragma unroll
      for (int c = 0; c < 4; c++) r[c] = *(const uint4*)(vb + adr[c]);
#pragma unroll
      for (int c = 0; c < 4; c++) bf8_fma(oa, ob, r[c], wc[c]);
    }
    // FR: group g = w*2+half holds channels g*8..g*8+7, swizzled by llm
    const int off = llq * 128 + (((w * 2 + half) ^ llm) << 3);
    uint4 st;
    st.x = ((unsigned)f2bf_rne(oa[1]) << 16) | f2bf_rne(oa[0]);
    st.y = ((unsigned)f2bf_rne(oa[3]) << 16) | f2bf_rne(oa[2]);
    st.z = ((unsigned)f2bf_rne(ob[1]) << 16) | f2bf_rne(ob[0]);
    st.w = ((unsigned)f2bf_rne(ob[3]) << 16) | f2bf_rne(ob[2]);
    *(uint4*)(FR + off) = st;
  }
  __syncthreads();

  // ---- out GEMM: 32m x 128n, 8 waves, wave = 16m x 32n; direct float4 stores ----
  {
    const int wm = (w & 1) * 16;
    const int wn = (w >> 1) * 32;
    floatx4 acc[2];
#pragma unroll
    for (int j = 0; j < 2; j++) acc[j] = {0.0f, 0.0f, 0.0f, 0.0f};
#pragma unroll
    for (int K0 = 0; K0 < 4; K0++) {
      const int m = wm + nl;
      const int off = m * 128 + (((K0 * 4 + q) ^ (m & 15)) << 3);
      const bf16x8 ah = *(bf16x8*)(FR + off);
#pragma unroll
      for (int j = 0; j < 2; j++) {
        const int n = wn + j * 16 + nl;
        const size_t o = (size_t)(K0 * 4 + q) * CM * 8 + n * 8;
        const bf16x8 wh = *(const bf16x8*)(wf_out + o);
        const bf16x8 wl = *(const bf16x8*)(wf_out + (size_t)CM * 128 + o);
        acc[j] = __builtin_amdgcn_mfma_f32_16x16x32_bf16(ah, wl, acc[j], 0, 0, 0);
        acc[j] = __builtin_amdgcn_mfma_f32_16x16x32_bf16(ah, wh, acc[j], 0, 0, 0);
      }
    }
    // C/D: col=nl -> n, rows q*4+r -> m (contiguous in bchw) => float4 store
#pragma unroll
    for (int j = 0; j < 2; j++) {
      const int gc = wn + j * 16 + nl;
      const float bv = b_out[gc];
      float4 st = {acc[j][0] + bv, acc[j][1] + bv, acc[j][2] + bv, acc[j][3] + bv};
      *(float4*)(out + ((size_t)b * CM + gc) * LTOT + ml0 + wm + q * 4) = st;
    }
  }
}

extern "C" void kernel_launch(void* const* d_in, const int* in_sizes, int n_in,
                              void* d_out, int out_size, void* d_ws, size_t ws_size,
                              hipStream_t stream) {
  const float* nbr    = (const float*)d_in[0];
  const float* ext    = (const float*)d_in[1];
  const float* W_val  = (const float*)d_in[2];
  const float* b_val  = (const float*)d_in[3];
  const float* W_off  = (const float*)d_in[4];
  const float* b_off  = (const float*)d_in[5];
  const float* W_attn = (const float*)d_in[6];
  const float* b_attn = (const float*)d_in[7];
  const float* W_out  = (const float*)d_in[8];
  const float* b_out  = (const float*)d_in[9];
  float* out = (float*)d_out;

  unsigned short* value = (unsigned short*)d_ws;             // 8.39 MB bf16 [b][h][l][16]
  unsigned short* wf_val = value + (size_t)HB * NHEAD * LTOT * DHD;  // 64 KB
  unsigned short* wf_qa  = wf_val + 128 * 128 * 2;           // 96 KB
  unsigned short* wf_out = wf_qa + 192 * 128 * 2;            // 64 KB
  float* bias_qa = (float*)(wf_out + 128 * 128 * 2);         // 768 B

  prep<<<56, 256, 0, stream>>>(W_val, W_off, W_attn, W_out, b_off, b_attn,
                               wf_val, wf_qa, wf_out, bias_qa);
  gemm_val<<<dim3(128, HB), 256, 0, stream>>>(nbr, wf_val, b_val, value);
  samp<<<dim3(128 * HB), 512, 0, stream>>>(ext, value, wf_qa, wf_out, bias_qa, b_out, out);
}